// Round 17
// baseline (233.205 us; speedup 1.0000x reference)
//
#include <hip/hip_runtime.h>

typedef __bf16 bf16x8 __attribute__((ext_vector_type(8)));
typedef float f32x4 __attribute__((ext_vector_type(4)));

typedef const void __attribute__((address_space(1))) gvoid_t;
typedef void __attribute__((address_space(3))) lvoid_t;

__device__ __forceinline__ void gload16(const void* g, void* l) {
  __builtin_amdgcn_global_load_lds((gvoid_t*)g, (lvoid_t*)l, 16, 0, 0);
}

__device__ __forceinline__ unsigned short f2b(float f) {
  unsigned int u = __builtin_bit_cast(unsigned int, f);
  u = (u + 0x7FFFu + ((u >> 16) & 1u)) >> 16;
  return (unsigned short)u;
}

// packed f32x2 -> bf16x2 (RNE, same rounding as f2b). No builtin on gfx950.
__device__ __forceinline__ unsigned cvt_pk_bf16(float lo, float hi) {
  unsigned r;
  asm("v_cvt_pk_bf16_f32 %0, %1, %2" : "=v"(r) : "v"(lo), "v"(hi));
  return r;
}

// ---------------- LayerNorm: fp32 [rows][1024] -> bf16 ----------------
__global__ __launch_bounds__(256) void ln_kernel(
    const float* __restrict__ x, const float* __restrict__ g,
    const float* __restrict__ b, unsigned short* __restrict__ out) {
  const int row = blockIdx.x;
  const int t = threadIdx.x;
  const float4 v = *(const float4*)(x + (size_t)row * 1024 + t * 4);
  float s1 = v.x + v.y + v.z + v.w;
  float s2 = v.x * v.x + v.y * v.y + v.z * v.z + v.w * v.w;
#pragma unroll
  for (int off = 32; off > 0; off >>= 1) {
    s1 += __shfl_down(s1, off, 64);
    s2 += __shfl_down(s2, off, 64);
  }
  __shared__ float red[8];
  const int wid = t >> 6;
  if ((t & 63) == 0) { red[wid] = s1; red[wid + 4] = s2; }
  __syncthreads();
  s1 = red[0] + red[1] + red[2] + red[3];
  s2 = red[4] + red[5] + red[6] + red[7];
  const float mu = s1 * (1.0f / 1024.0f);
  const float var = s2 * (1.0f / 1024.0f) - mu * mu;
  const float rs = rsqrtf(var + 1e-5f);
  const float4 gv = *(const float4*)(g + t * 4);
  const float4 bv = *(const float4*)(b + t * 4);
  ushort4 o;
  o.x = f2b((v.x - mu) * rs * gv.x + bv.x);
  o.y = f2b((v.y - mu) * rs * gv.y + bv.y);
  o.z = f2b((v.z - mu) * rs * gv.z + bv.z);
  o.w = f2b((v.w - mu) * rs * gv.w + bv.w);
  *(ushort4*)(out + (size_t)row * 1024 + t * 4) = o;
}

// ------- transpose + fp32->bf16 convert: W[K][N] -> Wt[N][K] bf16 -------
__global__ __launch_bounds__(256) void convT_kernel(
    const float* __restrict__ W, unsigned short* __restrict__ Wt,
    int K, int N) {
  __shared__ float tl[32][33];
  const int n0 = blockIdx.x * 32, k0 = blockIdx.y * 32;
  const int tx = threadIdx.x & 31, ty = threadIdx.x >> 5;  // ty 0..7
#pragma unroll
  for (int i = 0; i < 4; ++i) {
    int k = ty + i * 8;
    tl[k][tx] = W[(size_t)(k0 + k) * N + n0 + tx];
  }
  __syncthreads();
#pragma unroll
  for (int i = 0; i < 4; ++i) {
    int n = ty + i * 8;
    Wt[(size_t)(n0 + n) * K + k0 + tx] = f2b(tl[tx][n]);
  }
}

// ---------------- bf16 MFMA GEMM 128x128, 4 waves, BK=64, 3-buf single-barrier (R11)
// EPI: 0 = bias -> fp32; 1 = bias + resid -> fp32; 2 = bias + GELU -> bf16; 3 = bias -> bf16
template <int EPI>
__global__ __launch_bounds__(256) void gemm_kernel(
    const unsigned short* __restrict__ A, const unsigned short* __restrict__ Bt,
    const float* __restrict__ bias, const float* __restrict__ resid,
    float* __restrict__ Cf, unsigned short* __restrict__ Cb,
    int M, int N, int K) {
  __shared__ __align__(16) char lds[98304];  // 3 bufs x (A 16K | B 16K)
  const int tid = threadIdx.x;
  const int lane = tid & 63, w = tid >> 6;
  const int wr = w >> 1, wc = w & 1;  // 2x2 waves, each 64x64 out
  const int bm0 = blockIdx.x * 128, bn0 = blockIdx.y * 128;

  f32x4 acc[4][4] = {};

  const int rr = lane >> 3;
  const int slog = (lane & 7) ^ rr;
  const unsigned short* gA = A + (size_t)(bm0 + w * 32 + rr) * K + slog * 8;
  const unsigned short* gB = Bt + (size_t)(bn0 + w * 32 + rr) * K + slog * 8;
  const size_t rstep8 = (size_t)8 * K;  // 8 rows down

  const int l15 = lane & 15;
  const int g = lane >> 4;  // k-group of this lane's MFMA fragment

  const int nt = K >> 6;  // BK=64

  auto STAGE = [&](int t, int buf) {
    const int k0 = t << 6;
    char* ab = lds + buf * 32768 + w * 4096;
    char* bb = lds + buf * 32768 + 16384 + w * 4096;
#pragma unroll
    for (int j = 0; j < 4; ++j) {
      gload16(gA + j * rstep8 + k0, ab + j * 1024);
      gload16(gB + j * rstep8 + k0, bb + j * 1024);
    }
  };

  STAGE(0, 0);
  STAGE(1 < nt ? 1 : 0, 1);
  int cur = 0;

  for (int t = 0; t < nt; ++t) {
    asm volatile("s_waitcnt vmcnt(8)" ::: "memory");
    __builtin_amdgcn_sched_barrier(0);
    __builtin_amdgcn_s_barrier();  // tile-t data in LDS; buf[(t-1)%3] dead
    __builtin_amdgcn_sched_barrier(0);

    const char* ldsA = lds + cur * 32768;
    const char* ldsB = ldsA + 16384;
#pragma unroll
    for (int kk = 0; kk < 2; ++kk) {
      bf16x8 af[4], bfr[4];
#pragma unroll
      for (int m = 0; m < 4; ++m) {
        const int tr = wr * 64 + m * 16 + l15;
        af[m] = *(const bf16x8*)(ldsA + tr * 128 + (((kk * 4 + g) ^ (tr & 7)) << 4));
      }
#pragma unroll
      for (int n = 0; n < 4; ++n) {
        const int tc = wc * 64 + n * 16 + l15;
        bfr[n] = *(const bf16x8*)(ldsB + tc * 128 + (((kk * 4 + g) ^ (tc & 7)) << 4));
      }
      __builtin_amdgcn_s_setprio(1);
#pragma unroll
      for (int m = 0; m < 4; ++m)
#pragma unroll
        for (int n = 0; n < 4; ++n)
          acc[m][n] =
              __builtin_amdgcn_mfma_f32_16x16x32_bf16(af[m], bfr[n], acc[m][n], 0, 0, 0);
      __builtin_amdgcn_s_setprio(0);
    }

    __builtin_amdgcn_sched_barrier(0);  // keep STAGE below reads/MFMA
    const int t2 = (t + 2 < nt) ? t + 2 : nt - 1;
    STAGE(t2, cur ? cur - 1 : 2);  // (cur+2)%3
    cur = (cur == 2) ? 0 : cur + 1;
  }

  // epilogue: C/D layout col = lane&15, row = (lane>>4)*4 + i
#pragma unroll
  for (int mm = 0; mm < 4; ++mm) {
    const int r0 = bm0 + wr * 64 + mm * 16 + (g << 2);
#pragma unroll
    for (int nn = 0; nn < 4; ++nn) {
      const int c = bn0 + wc * 64 + nn * 16 + l15;
      const float bv = bias[c];
#pragma unroll
      for (int i = 0; i < 4; ++i) {
        const size_t idx = (size_t)(r0 + i) * N + c;
        float v = acc[mm][nn][i] + bv;
        if constexpr (EPI == 1) {
          v += resid[idx];
          Cf[idx] = v;
        } else if constexpr (EPI == 2) {
          v = 0.5f * v * (1.0f + erff(v * 0.70710678118654752f));
          Cb[idx] = f2b(v);
        } else if constexpr (EPI == 3) {
          Cb[idx] = f2b(v);
        } else {
          Cf[idx] = v;
        }
      }
    }
  }
}

// ---------------- bf16 MFMA GEMM 256x128, 8 waves, BK=64, 3-buf single-barrier ----
// 32 MFMAs per barrier epoch (vs 16 at BK=32). LDS 3 x (A 32K | B 16K) = 144KB,
// 1 block/CU. 6 gloads/stage (4A+2B), 2 stages outstanding -> vmcnt(6).
// 128B rows, XOR swizzle slot^(row&7) (R11-proven). EPI=3 (QKV) scatters V part
// (cols >= 2048) into vt[bh][64][2048].
template <int EPI>
__global__ __launch_bounds__(512) void gemm8w_kernel(
    const unsigned short* __restrict__ A, const unsigned short* __restrict__ Bt,
    const float* __restrict__ bias, const float* __restrict__ resid,
    float* __restrict__ Cf, unsigned short* __restrict__ Cb,
    unsigned short* __restrict__ vtp,
    int M, int N, int K) {
  __shared__ __align__(16) char lds[147456];  // 3 bufs x (A 32K | B 16K)
  const int tid = threadIdx.x;
  const int lane = tid & 63, w = tid >> 6;  // w 0..7
  const int wr = w >> 1, wc = w & 1;        // 4x2 waves, each 64x64 out
  const int bm0 = blockIdx.x * 256, bn0 = blockIdx.y * 128;

  f32x4 acc[4][4] = {};

  const int rr = lane >> 3;            // row within 8-row group
  const int slog = (lane & 7) ^ rr;    // source k-slot (XOR involution)
  const unsigned short* gA = A + (size_t)(bm0 + w * 32 + rr) * K + slog * 8;
  const unsigned short* gB = Bt + (size_t)(bn0 + w * 16 + rr) * K + slog * 8;
  const size_t rstep8 = (size_t)8 * K;

  const int l15 = lane & 15;
  const int g = lane >> 4;

  const int nt = K >> 6;  // BK=64

  auto STAGE = [&](int t, int buf) {
    const int k0 = t << 6;
    char* ab = lds + buf * 49152 + w * 4096;          // A: rows w*32..+32
    char* bb = lds + buf * 49152 + 32768 + w * 2048;  // B: rows w*16..+16
#pragma unroll
    for (int j = 0; j < 4; ++j) gload16(gA + j * rstep8 + k0, ab + j * 1024);
#pragma unroll
    for (int j = 0; j < 2; ++j) gload16(gB + j * rstep8 + k0, bb + j * 1024);
  };

  STAGE(0, 0);
  STAGE(1 < nt ? 1 : 0, 1);
  int cur = 0;

  for (int t = 0; t < nt; ++t) {
    asm volatile("s_waitcnt vmcnt(6)" ::: "memory");
    __builtin_amdgcn_sched_barrier(0);
    __builtin_amdgcn_s_barrier();  // tile-t data in LDS; buf[(t-1)%3] dead
    __builtin_amdgcn_sched_barrier(0);

    const char* ldsA = lds + cur * 49152;
    const char* ldsB = ldsA + 32768;
#pragma unroll
    for (int kk = 0; kk < 2; ++kk) {
      bf16x8 af[4], bfr[4];
#pragma unroll
      for (int m = 0; m < 4; ++m) {
        const int tr = wr * 64 + m * 16 + l15;  // 0..255
        af[m] = *(const bf16x8*)(ldsA + tr * 128 + (((kk * 4 + g) ^ (tr & 7)) << 4));
      }
#pragma unroll
      for (int n = 0; n < 4; ++n) {
        const int tc = wc * 64 + n * 16 + l15;  // 0..127
        bfr[n] = *(const bf16x8*)(ldsB + tc * 128 + (((kk * 4 + g) ^ (tc & 7)) << 4));
      }
      __builtin_amdgcn_s_setprio(1);
#pragma unroll
      for (int m = 0; m < 4; ++m)
#pragma unroll
        for (int n = 0; n < 4; ++n)
          acc[m][n] =
              __builtin_amdgcn_mfma_f32_16x16x32_bf16(af[m], bfr[n], acc[m][n], 0, 0, 0);
      __builtin_amdgcn_s_setprio(0);
    }

    __builtin_amdgcn_sched_barrier(0);
    const int t2 = (t + 2 < nt) ? t + 2 : nt - 1;
    STAGE(t2, cur ? cur - 1 : 2);  // (cur+2)%3 == (cur-1)%3
    cur = (cur == 2) ? 0 : cur + 1;
  }

  // epilogue: C/D layout col = lane&15, row = (lane>>4)*4 + i
#pragma unroll
  for (int mm = 0; mm < 4; ++mm) {
    const int r0 = bm0 + wr * 64 + mm * 16 + (g << 2);
#pragma unroll
    for (int nn = 0; nn < 4; ++nn) {
      const int c = bn0 + wc * 64 + nn * 16 + l15;
      const float bv = bias[c];
#pragma unroll
      for (int i = 0; i < 4; ++i) {
        const size_t idx = (size_t)(r0 + i) * N + c;
        float v = acc[mm][nn][i] + bv;
        if constexpr (EPI == 1) {
          v += resid[idx];
          Cf[idx] = v;
        } else if constexpr (EPI == 2) {
          v = 0.5f * v * (1.0f + erff(v * 0.70710678118654752f));
          Cb[idx] = f2b(v);
        } else if constexpr (EPI == 3) {
          const unsigned short bvs = f2b(v);
          Cb[idx] = bvs;
          if (c >= 2048) {  // V part -> vt[bh=b*16+h][d][s_local]
            const int row = r0 + i;
            const int d = c - 2048;
            vtp[((size_t)((row >> 11) * 16 + (d >> 6)) * 64 + (d & 63)) * 2048 +
                (row & 2047)] = bvs;
          }
        } else {
          Cf[idx] = v;
        }
      }
    }
  }
}

// ---------------- causal flash attention, QBLK=128, 8 waves, no-max softmax ----
// grid: x = B*H (32), y = S/128 (16); block = 512
__global__ __launch_bounds__(512) void attn_mfma_kernel(
    const unsigned short* __restrict__ qkv, const unsigned short* __restrict__ vt,
    unsigned short* __restrict__ out) {
  __shared__ __align__(16) char Kl[24576];  // 3 bufs x [64 key][128B d]
  __shared__ __align__(16) char Vl[24576];  // 3 bufs x [64 d][128B key]
  __shared__ __align__(16) char Pl[16384];  // 8 waves x [16 q][64 key] bf16, swizzled
  const int bh = blockIdx.x;
  const int b = bh >> 4, h = bh & 15;
  const int qtile = (int)gridDim.y - 1 - (int)blockIdx.y;  // longest blocks dispatch first
  const int q0 = qtile * 128;
  const int tid = threadIdx.x;
  const int lane = tid & 63, w = tid >> 6;  // w 0..7, wave owns q rows [q0+w*16, +16)
  const int l15 = lane & 15, g = lane >> 4;
  const size_t rowbase = (size_t)b * 2048;
  const float SC2 = 0.18033688011112042f;  // 0.125 * log2(e)

  // Q A-fragments (row = l15, k-slice = g*8, two k-tiles of 32)
  bf16x8 aq[2];
  {
    const unsigned short* qp = qkv + (rowbase + q0 + w * 16 + l15) * 3072 + h * 64 + g * 8;
    aq[0] = __builtin_bit_cast(bf16x8, *(const uint4*)qp);
    aq[1] = __builtin_bit_cast(bf16x8, *(const uint4*)(qp + 32));
  }

  f32x4 oacc[4] = {};
  float lrow[4] = {0.f, 0.f, 0.f, 0.f};

  // staging: wave w covers rows [w*8, w*8+8) of the 64-row K and V tiles (1KB each).
  const int srow = w * 8 + (lane >> 3);
  const int slog = (lane & 7) ^ (lane >> 3);  // srow&7 == lane>>3
  const unsigned short* kS = qkv + (rowbase + srow) * 3072 + 1024 + h * 64 + slog * 8;
  const unsigned short* vS = vt + ((size_t)bh * 64 + srow) * 2048 + slog * 8;
  const int nt = 2 * qtile + 2;

  auto STAGE = [&](int t, int buf) {
    const int kb = t * 64;
    gload16(kS + (size_t)kb * 3072, Kl + buf * 8192 + w * 1024);
    gload16(vS + kb, Vl + buf * 8192 + w * 1024);
  };

  STAGE(0, 0);
  STAGE(1 < nt ? 1 : 0, 1);
  int cur = 0;

  for (int kt = 0; kt < nt; ++kt) {
    const int kb = kt * 64;
    asm volatile("s_waitcnt vmcnt(2)" ::: "memory");
    __builtin_amdgcn_sched_barrier(0);
    __builtin_amdgcn_s_barrier();  // tile-kt data in LDS; buf[(kt-1)%3] dead
    __builtin_amdgcn_sched_barrier(0);

    const char* Kc = Kl + cur * 8192;
    const char* Vc = Vl + cur * 8192;

    // S = Q K^T  (C layout: col=key=l15+16n, row=q=g*4+i)
    f32x4 sacc[4] = {};
    __builtin_amdgcn_s_setprio(1);
#pragma unroll
    for (int kk = 0; kk < 2; ++kk) {
#pragma unroll
      for (int n = 0; n < 4; ++n) {
        const int r = n * 16 + l15;
        bf16x8 bk = *(const bf16x8*)(Kc + r * 128 + (((kk * 4 + g) ^ (r & 7)) << 4));
        sacc[n] = __builtin_amdgcn_mfma_f32_16x16x32_bf16(aq[kk], bk, sacc[n], 0, 0, 0);
      }
    }
    __builtin_amdgcn_s_setprio(0);

    // no-max softmax accumulate: p = exp2(s*SC2), masked -> 0
    const bool diag = (kb + 63 > q0 + w * 16);
    float p[4][4];  // [n][i]
#pragma unroll
    for (int i = 0; i < 4; ++i) {
      const int qrel = q0 + w * 16 + g * 4 + i - kb;  // q relative to tile base
      float ls = 0.f;
#pragma unroll
      for (int n = 0; n < 4; ++n) {
        float pv = __builtin_amdgcn_exp2f(sacc[n][i] * SC2);
        if (diag && (l15 + 16 * n > qrel)) pv = 0.f;
        p[n][i] = pv;
        ls += pv;
      }
      lrow[i] += ls;
    }

    // P -> bf16 (packed cvt) -> per-wave LDS region (A-layout source), then PV
#pragma unroll
    for (int n = 0; n < 4; ++n) {
      const int col = l15 + 16 * n;
#pragma unroll
      for (int i = 0; i < 4; i += 2) {
        const unsigned pk = cvt_pk_bf16(p[n][i], p[n][i + 1]);  // lo=row i, hi=row i+1
        const int r0b = g * 4 + i, r1b = g * 4 + i + 1;
        *(unsigned short*)(Pl + w * 2048 + ((r0b * 128 + col * 2) ^ ((r0b & 7) << 4))) =
            (unsigned short)pk;
        *(unsigned short*)(Pl + w * 2048 + ((r1b * 128 + col * 2) ^ ((r1b & 7) << 4))) =
            (unsigned short)(pk >> 16);
      }
    }
#pragma unroll
    for (int kk = 0; kk < 2; ++kk) {
      bf16x8 ap = *(const bf16x8*)(Pl + w * 2048 + ((l15 * 128 + g * 16 + kk * 64) ^ ((l15 & 7) << 4)));
      __builtin_amdgcn_s_setprio(1);
#pragma unroll
      for (int dn = 0; dn < 4; ++dn) {
        const int r = dn * 16 + l15;
        bf16x8 bv = *(const bf16x8*)(Vc + r * 128 + (((kk * 4 + g) ^ (r & 7)) << 4));
        oacc[dn] = __builtin_amdgcn_mfma_f32_16x16x32_bf16(ap, bv, oacc[dn], 0, 0, 0);
      }
      __builtin_amdgcn_s_setprio(0);
    }

    __builtin_amdgcn_sched_barrier(0);  // keep STAGE below all LDS reads
    const int t2 = (kt + 2 < nt) ? kt + 2 : nt - 1;
    STAGE(t2, cur ? cur - 1 : 2);
    cur = (cur == 2) ? 0 : cur + 1;
  }

  // final: reduce l across the 16-lane row group, normalize, store
#pragma unroll
  for (int i = 0; i < 4; ++i) {
    float l = lrow[i];
#pragma unroll
    for (int off = 8; off >= 1; off >>= 1) l += __shfl_xor(l, off, 64);
    const float inv = 1.0f / l;
    unsigned short* op = out + (rowbase + q0 + w * 16 + g * 4 + i) * 1024 + h * 64 + l15;
#pragma unroll
    for (int dn = 0; dn < 4; ++dn) op[dn * 16] = f2b(oacc[dn][i] * inv);
  }
}

extern "C" void kernel_launch(void* const* d_in, const int* in_sizes, int n_in,
                              void* d_out, int out_size, void* d_ws, size_t ws_size,
                              hipStream_t stream) {
  const float* x = (const float*)d_in[0];
  const float* ln1_g = (const float*)d_in[2];
  const float* ln1_b = (const float*)d_in[3];
  const float* Wqkv = (const float*)d_in[4];
  const float* bqkv = (const float*)d_in[5];
  const float* Wo = (const float*)d_in[6];
  const float* bo = (const float*)d_in[7];
  const float* ln2_g = (const float*)d_in[8];
  const float* ln2_b = (const float*)d_in[9];
  const float* W1 = (const float*)d_in[10];
  const float* b1 = (const float*)d_in[11];
  const float* W2 = (const float*)d_in[12];
  const float* b2 = (const float*)d_in[13];
  float* outp = (float*)d_out;

  const int M = 4096, D = 1024, F = 4096;
  char* ws = (char*)d_ws;
  size_t o = 0;
  auto alloc = [&](size_t bytes) {
    size_t r = o;
    o += (bytes + 255) & ~(size_t)255;
    return r;
  };
  unsigned short* bWqkv = (unsigned short*)(ws + alloc((size_t)3072 * D * 2));
  unsigned short* bWo   = (unsigned short*)(ws + alloc((size_t)D * D * 2));
  unsigned short* bW1   = (unsigned short*)(ws + alloc((size_t)F * D * 2));
  unsigned short* bW2   = (unsigned short*)(ws + alloc((size_t)D * F * 2));
  unsigned short* h     = (unsigned short*)(ws + alloc((size_t)M * D * 2));   // also h2
  unsigned short* qkvb  = (unsigned short*)(ws + alloc((size_t)M * F * 2));   // qkv bf16; also f1
  unsigned short* attn  = (unsigned short*)(ws + alloc((size_t)M * D * 2));
  float* x1             = (float*)(ws + alloc((size_t)M * D * 4));
  unsigned short* vt    = (unsigned short*)(ws + alloc((size_t)32 * 64 * 2048 * 2));
  unsigned short* f1 = qkvb;
  unsigned short* h2 = h;

  // weight transpose+convert: Wt[N][K]
  convT_kernel<<<dim3(3072 / 32, D / 32), 256, 0, stream>>>(Wqkv, bWqkv, D, 3072);
  convT_kernel<<<dim3(D / 32, D / 32), 256, 0, stream>>>(Wo, bWo, D, D);
  convT_kernel<<<dim3(F / 32, D / 32), 256, 0, stream>>>(W1, bW1, D, F);
  convT_kernel<<<dim3(D / 32, F / 32), 256, 0, stream>>>(W2, bW2, F, D);

  // LN1
  ln_kernel<<<M, 256, 0, stream>>>(x, ln1_g, ln1_b, h);
  // QKV = h @ Wqkv + bqkv   (bf16 out + fused V-transpose)  [256x128 8-wave BK=64]
  gemm8w_kernel<3><<<dim3(M / 256, 3072 / 128), 512, 0, stream>>>(
      h, bWqkv, bqkv, nullptr, nullptr, qkvb, vt, M, 3072, D);
  // attention -> bf16 [M][D]   [QBLK=128, 8 waves]
  attn_mfma_kernel<<<dim3(32, 16), 512, 0, stream>>>(qkvb, vt, attn);
  // x1 = attn @ Wo + bo + x  (fp32)   [BK=64 4-wave]
  gemm_kernel<1><<<dim3(M / 128, D / 128), 256, 0, stream>>>(
      attn, bWo, bo, x, x1, nullptr, M, D, D);
  // LN2
  ln_kernel<<<M, 256, 0, stream>>>(x1, ln2_g, ln2_b, h2);
  // f1 = gelu(h2 @ W1 + b1)  (bf16)  [256x128 8-wave BK=64]
  gemm8w_kernel<2><<<dim3(M / 256, F / 128), 512, 0, stream>>>(
      h2, bW1, b1, nullptr, nullptr, f1, nullptr, M, F, D);
  // out = f1 @ W2 + b2 + x1  (fp32)   [BK=64 4-wave]
  gemm_kernel<1><<<dim3(M / 128, D / 128), 256, 0, stream>>>(
      f1, bW2, b2, x1, outp, nullptr, M, D, F);
}

// Round 18
// 216.125 us; speedup vs baseline: 1.0790x; 1.0790x over previous
//
#include <hip/hip_runtime.h>

typedef __bf16 bf16x8 __attribute__((ext_vector_type(8)));
typedef float f32x4 __attribute__((ext_vector_type(4)));

typedef const void __attribute__((address_space(1))) gvoid_t;
typedef void __attribute__((address_space(3))) lvoid_t;

__device__ __forceinline__ void gload16(const void* g, void* l) {
  __builtin_amdgcn_global_load_lds((gvoid_t*)g, (lvoid_t*)l, 16, 0, 0);
}

__device__ __forceinline__ unsigned short f2b(float f) {
  unsigned int u = __builtin_bit_cast(unsigned int, f);
  u = (u + 0x7FFFu + ((u >> 16) & 1u)) >> 16;
  return (unsigned short)u;
}

// packed f32x2 -> bf16x2 (RNE, same rounding as f2b). No builtin on gfx950.
__device__ __forceinline__ unsigned cvt_pk_bf16(float lo, float hi) {
  unsigned r;
  asm("v_cvt_pk_bf16_f32 %0, %1, %2" : "=v"(r) : "v"(lo), "v"(hi));
  return r;
}

// ---------------- LayerNorm: fp32 [rows][1024] -> bf16 ----------------
__global__ __launch_bounds__(256) void ln_kernel(
    const float* __restrict__ x, const float* __restrict__ g,
    const float* __restrict__ b, unsigned short* __restrict__ out) {
  const int row = blockIdx.x;
  const int t = threadIdx.x;
  const float4 v = *(const float4*)(x + (size_t)row * 1024 + t * 4);
  float s1 = v.x + v.y + v.z + v.w;
  float s2 = v.x * v.x + v.y * v.y + v.z * v.z + v.w * v.w;
#pragma unroll
  for (int off = 32; off > 0; off >>= 1) {
    s1 += __shfl_down(s1, off, 64);
    s2 += __shfl_down(s2, off, 64);
  }
  __shared__ float red[8];
  const int wid = t >> 6;
  if ((t & 63) == 0) { red[wid] = s1; red[wid + 4] = s2; }
  __syncthreads();
  s1 = red[0] + red[1] + red[2] + red[3];
  s2 = red[4] + red[5] + red[6] + red[7];
  const float mu = s1 * (1.0f / 1024.0f);
  const float var = s2 * (1.0f / 1024.0f) - mu * mu;
  const float rs = rsqrtf(var + 1e-5f);
  const float4 gv = *(const float4*)(g + t * 4);
  const float4 bv = *(const float4*)(b + t * 4);
  ushort4 o;
  o.x = f2b((v.x - mu) * rs * gv.x + bv.x);
  o.y = f2b((v.y - mu) * rs * gv.y + bv.y);
  o.z = f2b((v.z - mu) * rs * gv.z + bv.z);
  o.w = f2b((v.w - mu) * rs * gv.w + bv.w);
  *(ushort4*)(out + (size_t)row * 1024 + t * 4) = o;
}

// ------- merged prep: 4x weight transpose/convert + LN1, one launch -------
// blocks 0..3071: Wqkv tiles; 3072..4095: Wo; 4096..8191: W1; 8192..12287: W2;
// 12288..16383: LN1 rows.
__global__ __launch_bounds__(256) void prep_kernel(
    const float* __restrict__ x, const float* __restrict__ ln1_g,
    const float* __restrict__ ln1_b,
    const float* __restrict__ Wqkv, const float* __restrict__ Wo,
    const float* __restrict__ W1, const float* __restrict__ W2,
    unsigned short* __restrict__ bWqkv, unsigned short* __restrict__ bWo,
    unsigned short* __restrict__ bW1, unsigned short* __restrict__ bW2,
    unsigned short* __restrict__ h) {
  __shared__ float tl[32][33];
  __shared__ float red[8];
  const int flat = blockIdx.x;
  const int t = threadIdx.x;
  if (flat >= 12288) {
    // ---- LN1 row ----
    const int row = flat - 12288;
    const float4 v = *(const float4*)(x + (size_t)row * 1024 + t * 4);
    float s1 = v.x + v.y + v.z + v.w;
    float s2 = v.x * v.x + v.y * v.y + v.z * v.z + v.w * v.w;
#pragma unroll
    for (int off = 32; off > 0; off >>= 1) {
      s1 += __shfl_down(s1, off, 64);
      s2 += __shfl_down(s2, off, 64);
    }
    const int wid = t >> 6;
    if ((t & 63) == 0) { red[wid] = s1; red[wid + 4] = s2; }
    __syncthreads();
    s1 = red[0] + red[1] + red[2] + red[3];
    s2 = red[4] + red[5] + red[6] + red[7];
    const float mu = s1 * (1.0f / 1024.0f);
    const float var = s2 * (1.0f / 1024.0f) - mu * mu;
    const float rs = rsqrtf(var + 1e-5f);
    const float4 gv = *(const float4*)(ln1_g + t * 4);
    const float4 bv = *(const float4*)(ln1_b + t * 4);
    ushort4 o;
    o.x = f2b((v.x - mu) * rs * gv.x + bv.x);
    o.y = f2b((v.y - mu) * rs * gv.y + bv.y);
    o.z = f2b((v.z - mu) * rs * gv.z + bv.z);
    o.w = f2b((v.w - mu) * rs * gv.w + bv.w);
    *(ushort4*)(h + (size_t)row * 1024 + t * 4) = o;
    return;
  }
  // ---- transpose + convert tile ----
  const float* W;
  unsigned short* Wt;
  int K, N, nx, f;
  if (flat < 3072)      { W = Wqkv; Wt = bWqkv; K = 1024; N = 3072; nx = 96;  f = flat; }
  else if (flat < 4096) { W = Wo;   Wt = bWo;   K = 1024; N = 1024; nx = 32;  f = flat - 3072; }
  else if (flat < 8192) { W = W1;   Wt = bW1;   K = 1024; N = 4096; nx = 128; f = flat - 4096; }
  else                  { W = W2;   Wt = bW2;   K = 4096; N = 1024; nx = 32;  f = flat - 8192; }
  const int n0 = (f % nx) * 32, k0 = (f / nx) * 32;
  const int tx = t & 31, ty = t >> 5;  // ty 0..7
#pragma unroll
  for (int i = 0; i < 4; ++i) {
    int k = ty + i * 8;
    tl[k][tx] = W[(size_t)(k0 + k) * N + n0 + tx];
  }
  __syncthreads();
#pragma unroll
  for (int i = 0; i < 4; ++i) {
    int n = ty + i * 8;
    Wt[(size_t)(n0 + n) * K + k0 + tx] = f2b(tl[tx][n]);
  }
}

// ---------------- bf16 MFMA GEMM 128x128, 4 waves, BK=64, 3-buf single-barrier (R11)
// EPI: 0 = bias -> fp32; 1 = bias + resid -> fp32; 2 = bias + GELU -> bf16; 3 = bias -> bf16
template <int EPI>
__global__ __launch_bounds__(256) void gemm_kernel(
    const unsigned short* __restrict__ A, const unsigned short* __restrict__ Bt,
    const float* __restrict__ bias, const float* __restrict__ resid,
    float* __restrict__ Cf, unsigned short* __restrict__ Cb,
    int M, int N, int K) {
  __shared__ __align__(16) char lds[98304];  // 3 bufs x (A 16K | B 16K)
  const int tid = threadIdx.x;
  const int lane = tid & 63, w = tid >> 6;
  const int wr = w >> 1, wc = w & 1;  // 2x2 waves, each 64x64 out
  const int bm0 = blockIdx.x * 128, bn0 = blockIdx.y * 128;

  f32x4 acc[4][4] = {};

  const int rr = lane >> 3;
  const int slog = (lane & 7) ^ rr;
  const unsigned short* gA = A + (size_t)(bm0 + w * 32 + rr) * K + slog * 8;
  const unsigned short* gB = Bt + (size_t)(bn0 + w * 32 + rr) * K + slog * 8;
  const size_t rstep8 = (size_t)8 * K;  // 8 rows down

  const int l15 = lane & 15;
  const int g = lane >> 4;  // k-group of this lane's MFMA fragment

  const int nt = K >> 6;  // BK=64

  auto STAGE = [&](int t, int buf) {
    const int k0 = t << 6;
    char* ab = lds + buf * 32768 + w * 4096;
    char* bb = lds + buf * 32768 + 16384 + w * 4096;
#pragma unroll
    for (int j = 0; j < 4; ++j) {
      gload16(gA + j * rstep8 + k0, ab + j * 1024);
      gload16(gB + j * rstep8 + k0, bb + j * 1024);
    }
  };

  STAGE(0, 0);
  STAGE(1 < nt ? 1 : 0, 1);
  int cur = 0;

  for (int t = 0; t < nt; ++t) {
    asm volatile("s_waitcnt vmcnt(8)" ::: "memory");
    __builtin_amdgcn_sched_barrier(0);
    __builtin_amdgcn_s_barrier();  // tile-t data in LDS; buf[(t-1)%3] dead
    __builtin_amdgcn_sched_barrier(0);

    const char* ldsA = lds + cur * 32768;
    const char* ldsB = ldsA + 16384;
#pragma unroll
    for (int kk = 0; kk < 2; ++kk) {
      bf16x8 af[4], bfr[4];
#pragma unroll
      for (int m = 0; m < 4; ++m) {
        const int tr = wr * 64 + m * 16 + l15;
        af[m] = *(const bf16x8*)(ldsA + tr * 128 + (((kk * 4 + g) ^ (tr & 7)) << 4));
      }
#pragma unroll
      for (int n = 0; n < 4; ++n) {
        const int tc = wc * 64 + n * 16 + l15;
        bfr[n] = *(const bf16x8*)(ldsB + tc * 128 + (((kk * 4 + g) ^ (tc & 7)) << 4));
      }
      __builtin_amdgcn_s_setprio(1);
#pragma unroll
      for (int m = 0; m < 4; ++m)
#pragma unroll
        for (int n = 0; n < 4; ++n)
          acc[m][n] =
              __builtin_amdgcn_mfma_f32_16x16x32_bf16(af[m], bfr[n], acc[m][n], 0, 0, 0);
      __builtin_amdgcn_s_setprio(0);
    }

    __builtin_amdgcn_sched_barrier(0);  // keep STAGE below reads/MFMA
    const int t2 = (t + 2 < nt) ? t + 2 : nt - 1;
    STAGE(t2, cur ? cur - 1 : 2);  // (cur+2)%3
    cur = (cur == 2) ? 0 : cur + 1;
  }

  // epilogue: C/D layout col = lane&15, row = (lane>>4)*4 + i
#pragma unroll
  for (int mm = 0; mm < 4; ++mm) {
    const int r0 = bm0 + wr * 64 + mm * 16 + (g << 2);
#pragma unroll
    for (int nn = 0; nn < 4; ++nn) {
      const int c = bn0 + wc * 64 + nn * 16 + l15;
      const float bv = bias[c];
#pragma unroll
      for (int i = 0; i < 4; ++i) {
        const size_t idx = (size_t)(r0 + i) * N + c;
        float v = acc[mm][nn][i] + bv;
        if constexpr (EPI == 1) {
          v += resid[idx];
          Cf[idx] = v;
        } else if constexpr (EPI == 2) {
          v = 0.5f * v * (1.0f + erff(v * 0.70710678118654752f));
          Cb[idx] = f2b(v);
        } else if constexpr (EPI == 3) {
          Cb[idx] = f2b(v);
        } else {
          Cf[idx] = v;
        }
      }
    }
  }
}

// ---------------- bf16 MFMA GEMM 256x128, 8 waves, BK=32, 3-buf single-barrier (R16)
// EPI=3 (QKV): K/Q cols -> Cb; V cols (>=2048) ONLY to vt[bh][64][2048]
// (qkvb's V region is dead -- attention reads V from vt).
template <int EPI>
__global__ __launch_bounds__(512) void gemm8w_kernel(
    const unsigned short* __restrict__ A, const unsigned short* __restrict__ Bt,
    const float* __restrict__ bias, const float* __restrict__ resid,
    float* __restrict__ Cf, unsigned short* __restrict__ Cb,
    unsigned short* __restrict__ vtp,
    int M, int N, int K) {
  __shared__ __align__(16) char lds[73728];  // 3 bufs x (A 16K | B 8K)
  const int tid = threadIdx.x;
  const int lane = tid & 63, w = tid >> 6;  // w 0..7
  const int wr = w >> 1, wc = w & 1;        // 4x2 waves, each 64x64 out
  const int bm0 = blockIdx.x * 256, bn0 = blockIdx.y * 128;

  f32x4 acc[4][4] = {};

  const int gcol = (lane & 3) ^ ((lane >> 3) & 3);
  const unsigned short* gA =
      A + (size_t)(bm0 + w * 32 + (lane >> 2)) * K + gcol * 8;
  const unsigned short* gB =
      Bt + (size_t)(bn0 + w * 16 + (lane >> 2)) * K + gcol * 8;
  const size_t rstep = (size_t)16 * K;

  const int l15 = lane & 15;
  const int g = lane >> 4;

  const int nt = K >> 5;

  auto STAGE = [&](int t, int buf) {
    const int k0 = t << 5;
    char* base = lds + buf * 24576;
    gload16(gA + k0, base + w * 2048);
    gload16(gA + rstep + k0, base + w * 2048 + 1024);
    gload16(gB + k0, base + 16384 + w * 1024);
  };

  STAGE(0, 0);
  STAGE(1 < nt ? 1 : 0, 1);
  int cur = 0;

  for (int t = 0; t < nt; ++t) {
    asm volatile("s_waitcnt vmcnt(3)" ::: "memory");
    __builtin_amdgcn_sched_barrier(0);
    __builtin_amdgcn_s_barrier();
    __builtin_amdgcn_sched_barrier(0);

    const char* ldsA = lds + cur * 24576;
    const char* ldsB = ldsA + 16384;
    bf16x8 af[4], bfr[4];
#pragma unroll
    for (int m = 0; m < 4; ++m) {
      const int tr = wr * 64 + m * 16 + l15;  // 0..255
      const int slot = g ^ ((tr >> 1) & 3);
      af[m] = *(const bf16x8*)(ldsA + tr * 64 + slot * 16);
    }
#pragma unroll
    for (int n = 0; n < 4; ++n) {
      const int tc = wc * 64 + n * 16 + l15;  // 0..127
      const int slot = g ^ ((tc >> 1) & 3);
      bfr[n] = *(const bf16x8*)(ldsB + tc * 64 + slot * 16);
    }
    __builtin_amdgcn_s_setprio(1);
#pragma unroll
    for (int m = 0; m < 4; ++m)
#pragma unroll
      for (int n = 0; n < 4; ++n)
        acc[m][n] =
            __builtin_amdgcn_mfma_f32_16x16x32_bf16(af[m], bfr[n], acc[m][n], 0, 0, 0);
    __builtin_amdgcn_s_setprio(0);

    __builtin_amdgcn_sched_barrier(0);
    const int t2 = (t + 2 < nt) ? t + 2 : nt - 1;
    STAGE(t2, cur ? cur - 1 : 2);
    cur = (cur == 2) ? 0 : cur + 1;
  }

  // epilogue: C/D layout col = lane&15, row = (lane>>4)*4 + i
#pragma unroll
  for (int mm = 0; mm < 4; ++mm) {
    const int r0 = bm0 + wr * 64 + mm * 16 + (g << 2);
#pragma unroll
    for (int nn = 0; nn < 4; ++nn) {
      const int c = bn0 + wc * 64 + nn * 16 + l15;
      const float bv = bias[c];
#pragma unroll
      for (int i = 0; i < 4; ++i) {
        const size_t idx = (size_t)(r0 + i) * N + c;
        float v = acc[mm][nn][i] + bv;
        if constexpr (EPI == 1) {
          v += resid[idx];
          Cf[idx] = v;
        } else if constexpr (EPI == 2) {
          v = 0.5f * v * (1.0f + erff(v * 0.70710678118654752f));
          Cb[idx] = f2b(v);
        } else if constexpr (EPI == 3) {
          const unsigned short bvs = f2b(v);
          if (c < 2048) {
            Cb[idx] = bvs;
          } else {  // V part -> vt[bh=b*16+h][d][s_local] only
            const int row = r0 + i;
            const int d = c - 2048;
            vtp[((size_t)((row >> 11) * 16 + (d >> 6)) * 64 + (d & 63)) * 2048 +
                (row & 2047)] = bvs;
          }
        } else {
          Cf[idx] = v;
        }
      }
    }
  }
}

// ---------------- causal flash attention, QBLK=128, 8 waves, no-max softmax ----
// grid: x = B*H (32), y = S/128 (16); block = 512
__global__ __launch_bounds__(512) void attn_mfma_kernel(
    const unsigned short* __restrict__ qkv, const unsigned short* __restrict__ vt,
    unsigned short* __restrict__ out) {
  __shared__ __align__(16) char Kl[24576];  // 3 bufs x [64 key][128B d]
  __shared__ __align__(16) char Vl[24576];  // 3 bufs x [64 d][128B key]
  __shared__ __align__(16) char Pl[16384];  // 8 waves x [16 q][64 key] bf16, swizzled
  const int bh = blockIdx.x;
  const int b = bh >> 4, h = bh & 15;
  const int qtile = (int)gridDim.y - 1 - (int)blockIdx.y;  // longest blocks dispatch first
  const int q0 = qtile * 128;
  const int tid = threadIdx.x;
  const int lane = tid & 63, w = tid >> 6;  // w 0..7, wave owns q rows [q0+w*16, +16)
  const int l15 = lane & 15, g = lane >> 4;
  const size_t rowbase = (size_t)b * 2048;
  const float SC2 = 0.18033688011112042f;  // 0.125 * log2(e)

  // Q A-fragments (row = l15, k-slice = g*8, two k-tiles of 32)
  bf16x8 aq[2];
  {
    const unsigned short* qp = qkv + (rowbase + q0 + w * 16 + l15) * 3072 + h * 64 + g * 8;
    aq[0] = __builtin_bit_cast(bf16x8, *(const uint4*)qp);
    aq[1] = __builtin_bit_cast(bf16x8, *(const uint4*)(qp + 32));
  }

  f32x4 oacc[4] = {};
  float lrow[4] = {0.f, 0.f, 0.f, 0.f};

  // staging: wave w covers rows [w*8, w*8+8) of the 64-row K and V tiles (1KB each).
  const int srow = w * 8 + (lane >> 3);
  const int slog = (lane & 7) ^ (lane >> 3);  // srow&7 == lane>>3
  const unsigned short* kS = qkv + (rowbase + srow) * 3072 + 1024 + h * 64 + slog * 8;
  const unsigned short* vS = vt + ((size_t)bh * 64 + srow) * 2048 + slog * 8;
  const int nt = 2 * qtile + 2;

  auto STAGE = [&](int t, int buf) {
    const int kb = t * 64;
    gload16(kS + (size_t)kb * 3072, Kl + buf * 8192 + w * 1024);
    gload16(vS + kb, Vl + buf * 8192 + w * 1024);
  };

  STAGE(0, 0);
  STAGE(1 < nt ? 1 : 0, 1);
  int cur = 0;

  for (int kt = 0; kt < nt; ++kt) {
    const int kb = kt * 64;
    asm volatile("s_waitcnt vmcnt(2)" ::: "memory");
    __builtin_amdgcn_sched_barrier(0);
    __builtin_amdgcn_s_barrier();  // tile-kt data in LDS; buf[(kt-1)%3] dead
    __builtin_amdgcn_sched_barrier(0);

    const char* Kc = Kl + cur * 8192;
    const char* Vc = Vl + cur * 8192;

    // S = Q K^T  (C layout: col=key=l15+16n, row=q=g*4+i)
    f32x4 sacc[4] = {};
    __builtin_amdgcn_s_setprio(1);
#pragma unroll
    for (int kk = 0; kk < 2; ++kk) {
#pragma unroll
      for (int n = 0; n < 4; ++n) {
        const int r = n * 16 + l15;
        bf16x8 bk = *(const bf16x8*)(Kc + r * 128 + (((kk * 4 + g) ^ (r & 7)) << 4));
        sacc[n] = __builtin_amdgcn_mfma_f32_16x16x32_bf16(aq[kk], bk, sacc[n], 0, 0, 0);
      }
    }
    __builtin_amdgcn_s_setprio(0);

    // no-max softmax accumulate: p = exp2(s*SC2), masked -> 0
    const bool diag = (kb + 63 > q0 + w * 16);
    float p[4][4];  // [n][i]
#pragma unroll
    for (int i = 0; i < 4; ++i) {
      const int qrel = q0 + w * 16 + g * 4 + i - kb;  // q relative to tile base
      float ls = 0.f;
#pragma unroll
      for (int n = 0; n < 4; ++n) {
        float pv = __builtin_amdgcn_exp2f(sacc[n][i] * SC2);
        if (diag && (l15 + 16 * n > qrel)) pv = 0.f;
        p[n][i] = pv;
        ls += pv;
      }
      lrow[i] += ls;
    }

    // P -> bf16 (packed cvt) -> per-wave LDS region (A-layout source), then PV
#pragma unroll
    for (int n = 0; n < 4; ++n) {
      const int col = l15 + 16 * n;
#pragma unroll
      for (int i = 0; i < 4; i += 2) {
        const unsigned pk = cvt_pk_bf16(p[n][i], p[n][i + 1]);  // lo=row i, hi=row i+1
        const int r0b = g * 4 + i, r1b = g * 4 + i + 1;
        *(unsigned short*)(Pl + w * 2048 + ((r0b * 128 + col * 2) ^ ((r0b & 7) << 4))) =
            (unsigned short)pk;
        *(unsigned short*)(Pl + w * 2048 + ((r1b * 128 + col * 2) ^ ((r1b & 7) << 4))) =
            (unsigned short)(pk >> 16);
      }
    }
#pragma unroll
    for (int kk = 0; kk < 2; ++kk) {
      bf16x8 ap = *(const bf16x8*)(Pl + w * 2048 + ((l15 * 128 + g * 16 + kk * 64) ^ ((l15 & 7) << 4)));
      __builtin_amdgcn_s_setprio(1);
#pragma unroll
      for (int dn = 0; dn < 4; ++dn) {
        const int r = dn * 16 + l15;
        bf16x8 bv = *(const bf16x8*)(Vc + r * 128 + (((kk * 4 + g) ^ (r & 7)) << 4));
        oacc[dn] = __builtin_amdgcn_mfma_f32_16x16x32_bf16(ap, bv, oacc[dn], 0, 0, 0);
      }
      __builtin_amdgcn_s_setprio(0);
    }

    __builtin_amdgcn_sched_barrier(0);  // keep STAGE below all LDS reads
    const int t2 = (kt + 2 < nt) ? kt + 2 : nt - 1;
    STAGE(t2, cur ? cur - 1 : 2);
    cur = (cur == 2) ? 0 : cur + 1;
  }

  // final: reduce l across the 16-lane row group, normalize, store
#pragma unroll
  for (int i = 0; i < 4; ++i) {
    float l = lrow[i];
#pragma unroll
    for (int off = 8; off >= 1; off >>= 1) l += __shfl_xor(l, off, 64);
    const float inv = 1.0f / l;
    unsigned short* op = out + (rowbase + q0 + w * 16 + g * 4 + i) * 1024 + h * 64 + l15;
#pragma unroll
    for (int dn = 0; dn < 4; ++dn) op[dn * 16] = f2b(oacc[dn][i] * inv);
  }
}

extern "C" void kernel_launch(void* const* d_in, const int* in_sizes, int n_in,
                              void* d_out, int out_size, void* d_ws, size_t ws_size,
                              hipStream_t stream) {
  const float* x = (const float*)d_in[0];
  const float* ln1_g = (const float*)d_in[2];
  const float* ln1_b = (const float*)d_in[3];
  const float* Wqkv = (const float*)d_in[4];
  const float* bqkv = (const float*)d_in[5];
  const float* Wo = (const float*)d_in[6];
  const float* bo = (const float*)d_in[7];
  const float* ln2_g = (const float*)d_in[8];
  const float* ln2_b = (const float*)d_in[9];
  const float* W1 = (const float*)d_in[10];
  const float* b1 = (const float*)d_in[11];
  const float* W2 = (const float*)d_in[12];
  const float* b2 = (const float*)d_in[13];
  float* outp = (float*)d_out;

  const int M = 4096, D = 1024, F = 4096;
  char* ws = (char*)d_ws;
  size_t o = 0;
  auto alloc = [&](size_t bytes) {
    size_t r = o;
    o += (bytes + 255) & ~(size_t)255;
    return r;
  };
  unsigned short* bWqkv = (unsigned short*)(ws + alloc((size_t)3072 * D * 2));
  unsigned short* bWo   = (unsigned short*)(ws + alloc((size_t)D * D * 2));
  unsigned short* bW1   = (unsigned short*)(ws + alloc((size_t)F * D * 2));
  unsigned short* bW2   = (unsigned short*)(ws + alloc((size_t)D * F * 2));
  unsigned short* h     = (unsigned short*)(ws + alloc((size_t)M * D * 2));   // also h2
  unsigned short* qkvb  = (unsigned short*)(ws + alloc((size_t)M * F * 2));   // qkv bf16; also f1
  unsigned short* attn  = (unsigned short*)(ws + alloc((size_t)M * D * 2));
  float* x1             = (float*)(ws + alloc((size_t)M * D * 4));
  unsigned short* vt    = (unsigned short*)(ws + alloc((size_t)32 * 64 * 2048 * 2));
  unsigned short* f1 = qkvb;
  unsigned short* h2 = h;

  // merged: 4x weight transpose/convert + LN1 (independent work, one launch)
  prep_kernel<<<16384, 256, 0, stream>>>(x, ln1_g, ln1_b, Wqkv, Wo, W1, W2,
                                         bWqkv, bWo, bW1, bW2, h);
  // QKV = h @ Wqkv + bqkv   (K/Q bf16 out + V direct to vt)  [256x128 8-wave BK=32]
  gemm8w_kernel<3><<<dim3(M / 256, 3072 / 128), 512, 0, stream>>>(
      h, bWqkv, bqkv, nullptr, nullptr, qkvb, vt, M, 3072, D);
  // attention -> bf16 [M][D]   [QBLK=128, 8 waves]
  attn_mfma_kernel<<<dim3(32, 16), 512, 0, stream>>>(qkvb, vt, attn);
  // x1 = attn @ Wo + bo + x  (fp32)   [BK=64 4-wave]
  gemm_kernel<1><<<dim3(M / 128, D / 128), 256, 0, stream>>>(
      attn, bWo, bo, x, x1, nullptr, M, D, D);
  // LN2
  ln_kernel<<<M, 256, 0, stream>>>(x1, ln2_g, ln2_b, h2);
  // f1 = gelu(h2 @ W1 + b1)  (bf16)  [256x128 8-wave BK=32]
  gemm8w_kernel<2><<<dim3(M / 256, F / 128), 512, 0, stream>>>(
      h2, bW1, b1, nullptr, nullptr, f1, nullptr, M, F, D);
  // out = f1 @ W2 + b2 + x1  (fp32)   [BK=64 4-wave]
  gemm_kernel<1><<<dim3(M / 128, D / 128), 256, 0, stream>>>(
      f1, bW2, b2, x1, outp, nullptr, M, D, F);
}